// Round 4
// baseline (510.919 us; speedup 1.0000x reference)
//
#include <hip/hip_runtime.h>
#include <hip/hip_bf16.h>

// ---------------- constants ----------------
#define Btok 16384
#define Ddim 1024
#define Eexp 8

typedef __attribute__((ext_vector_type(8))) short short8;
typedef __attribute__((ext_vector_type(4))) float f32x4;

__device__ inline unsigned short f2bf(float f) {
    unsigned int u = __float_as_uint(f);
    unsigned int r = (u + 0x7fffu + ((u >> 16) & 1u)) >> 16;
    return (unsigned short)r;
}

__device__ inline void gload16(const void* g, void* l) {
    __builtin_amdgcn_global_load_lds(
        (const __attribute__((address_space(1))) void*)g,
        (__attribute__((address_space(3))) void*)l, 16, 0, 0);
}

#define MEMF() asm volatile("" ::: "memory")
#define BARRIER() do { MEMF(); __builtin_amdgcn_s_barrier(); MEMF(); } while (0)
#define VMW(n) do { asm volatile("s_waitcnt vmcnt(" #n ")" ::: "memory"); \
                    __builtin_amdgcn_sched_barrier(0); } while (0)

// ---------------- tiny precompute kernels (f64 accum for gate accuracy) ----------------
// tmp[d][e] = sum_k Wo[d][k] * Wg[k][e]
__global__ __launch_bounds__(256) void k_tmp(const float* __restrict__ Wo,
                                             const float* __restrict__ Wg,
                                             float* __restrict__ tmp) {
    int id = blockIdx.x * 256 + threadIdx.x;   // 8192
    int d = id >> 3, e = id & 7;
    double s = 0.0;
    for (int k = 0; k < Ddim; ++k)
        s += (double)Wo[(long)d * Ddim + k] * (double)Wg[k * Eexp + e];
    tmp[id] = (float)s;
}

// WcT[e][d] = sum_k Wv[d][k] * tmp[k][e]
__global__ __launch_bounds__(256) void k_wc(const float* __restrict__ Wv,
                                            const float* __restrict__ tmp,
                                            float* __restrict__ WcT) {
    int id = blockIdx.x * 256 + threadIdx.x;   // 8192
    int d = id >> 3, e = id & 7;
    double s = 0.0;
    for (int k = 0; k < Ddim; ++k)
        s += (double)Wv[(long)d * Ddim + k] * (double)tmp[k * Eexp + e];
    WcT[e * Ddim + d] = (float)s;
}

// bcomb[e] = bv@tmp + bo@Wg + bg   (block of 512 = 8 waves, wave e)
__global__ __launch_bounds__(512) void k_bc(const float* __restrict__ bv,
                                            const float* __restrict__ bo,
                                            const float* __restrict__ bg,
                                            const float* __restrict__ Wg,
                                            const float* __restrict__ tmp,
                                            float* __restrict__ bcomb) {
    int w = threadIdx.x >> 6, l = threadIdx.x & 63;
    double s = 0.0;
    for (int k = l; k < Ddim; k += 64)
        s += (double)bv[k] * (double)tmp[k * Eexp + w] +
             (double)bo[k] * (double)Wg[k * Eexp + w];
    #pragma unroll
    for (int off = 32; off; off >>= 1) s += __shfl_xor(s, off);
    if (l == 0) bcomb[w] = (float)s + bg[w];
}

// ---------------- conversions ----------------
// x (f32) -> xb (bf16), 4 elems/thread
__global__ __launch_bounds__(256) void k_convx(const float4* __restrict__ x,
                                               ushort4* __restrict__ xb) {
    int i = blockIdx.x * 256 + threadIdx.x;
    float4 v = x[i];
    ushort4 o;
    o.x = f2bf(v.x); o.y = f2bf(v.y); o.z = f2bf(v.z); o.w = f2bf(v.w);
    xb[i] = o;
}

// W1,W2 (f32 [e][d][n]) -> transposed bf16 [e][n][d]
__global__ __launch_bounds__(256) void k_convw(const float* __restrict__ W1,
                                               const float* __restrict__ W2,
                                               unsigned short* __restrict__ w1bT,
                                               unsigned short* __restrict__ w2bT) {
    __shared__ float tile[32][33];
    int bid = blockIdx.x;             // 2*8*32*32 = 16384
    int arr = bid >> 13;
    int e = (bid >> 10) & 7, bi = (bid >> 5) & 31, bj = bid & 31;
    const float* src = (arr ? W2 : W1) + (long)e * Ddim * Ddim;
    unsigned short* dst = (arr ? w2bT : w1bT) + (long)e * Ddim * Ddim;
    int tr = threadIdx.x >> 5, tc = threadIdx.x & 31;
    #pragma unroll
    for (int i = 0; i < 4; ++i) {
        int dl = tr + i * 8;
        tile[dl][tc] = src[(long)(bi * 32 + dl) * Ddim + bj * 32 + tc];
    }
    __syncthreads();
    #pragma unroll
    for (int i = 0; i < 4; ++i) {
        int nl = tr + i * 8;
        dst[(long)(bj * 32 + nl) * Ddim + bi * 32 + tc] = f2bf(tile[tc][nl]);
    }
}

// ---------------- gate: logits -> softmax -> top2 (NO atomics) ----------------
__global__ __launch_bounds__(256) void k_gate(const float* __restrict__ q,
                                              const float* __restrict__ WcT,
                                              const float* __restrict__ bcomb,
                                              float* __restrict__ gate_prob,
                                              int* __restrict__ choice,
                                              float2* __restrict__ w12,
                                              float* __restrict__ impP) {
    __shared__ float impL[4][8];
    int w = threadIdx.x >> 6, l = threadIdx.x & 63;
    int t = blockIdx.x * 4 + w;
    const float* qr = q + (long)t * Ddim;
    float acc[8] = {0, 0, 0, 0, 0, 0, 0, 0};
    #pragma unroll
    for (int i = 0; i < 4; ++i) {
        float4 qv = *(const float4*)(qr + (i * 64 + l) * 4);
        #pragma unroll
        for (int e = 0; e < 8; ++e) {
            float4 wv = *(const float4*)(WcT + e * Ddim + (i * 64 + l) * 4);
            acc[e] += qv.x * wv.x + qv.y * wv.y + qv.z * wv.z + qv.w * wv.w;
        }
    }
    #pragma unroll
    for (int off = 32; off; off >>= 1)
        #pragma unroll
        for (int e = 0; e < 8; ++e) acc[e] += __shfl_xor(acc[e], off);
    // all lanes now hold full logits
    float lg[8], p[8];
    float m = -1e30f;
    #pragma unroll
    for (int e = 0; e < 8; ++e) { lg[e] = acc[e] + bcomb[e]; m = fmaxf(m, lg[e]); }
    float s = 0.f;
    #pragma unroll
    for (int e = 0; e < 8; ++e) { p[e] = expf(lg[e] - m); s += p[e]; }
    float inv = 1.f / s;
    #pragma unroll
    for (int e = 0; e < 8; ++e) p[e] *= inv;
    // top-2 (ties -> lower index, matching lax.top_k)
    float p1 = -1.f, p2 = -1.f; int i1 = 0, i2 = 0;
    #pragma unroll
    for (int e = 0; e < 8; ++e) {
        float pe = p[e];
        if (pe > p1) { p2 = p1; i2 = i1; p1 = pe; i1 = e; }
        else if (pe > p2) { p2 = pe; i2 = e; }
    }
    // softmax over the two PROBABILITY values (per reference)
    float ee = expf(p2 - p1);
    float wa = 1.f / (1.f + ee);
    float wb = ee / (1.f + ee);
    if (l == 0) {
        #pragma unroll
        for (int e = 0; e < 8; ++e) gate_prob[(long)t * 8 + e] = p[e];
        #pragma unroll
        for (int e = 0; e < 8; ++e) impL[w][e] = p[e];
        choice[t] = i1 | (i2 << 8);
        w12[t] = make_float2(wa, wb);
    }
    __syncthreads();
    if (threadIdx.x < 8)
        impP[blockIdx.x * 8 + threadIdx.x] =
            impL[0][threadIdx.x] + impL[1][threadIdx.x] +
            impL[2][threadIdx.x] + impL[3][threadIdx.x];
}

// ---------------- routing: hierarchical histogram + scatter ----------------
__global__ __launch_bounds__(256) void k_route(const int* __restrict__ choice,
                                               const float2* __restrict__ w12,
                                               int* __restrict__ counts,
                                               int* __restrict__ tok,
                                               float* __restrict__ wgt) {
    __shared__ int cnt[8];
    __shared__ int base[8];
    if (threadIdx.x < 8) cnt[threadIdx.x] = 0;
    __syncthreads();
    int t = blockIdx.x * 256 + threadIdx.x;
    int ch = choice[t];
    int i1 = ch & 255, i2 = ch >> 8;
    float2 ww = w12[t];
    int lp1 = atomicAdd(&cnt[i1], 1);
    int lp2 = atomicAdd(&cnt[i2], 1);
    __syncthreads();
    if (threadIdx.x < 8)
        base[threadIdx.x] = atomicAdd(&counts[threadIdx.x], cnt[threadIdx.x]);
    __syncthreads();
    int p1 = base[i1] + lp1;
    tok[i1 * Btok + p1] = t; wgt[i1 * Btok + p1] = ww.x;
    int p2 = base[i2] + lp2;
    tok[i2 * Btok + p2] = t; wgt[i2 * Btok + p2] = ww.y;
}

// ---------------- expert GEMMs: 256x256 tile, BK=64, 8-phase counted-vmcnt ----------------
// Phases = block C-quadrants (128x128). LDS: A[2buf][2half][128][128B] @0,
// B same @64KB. Staging order per tile: A0,B0,A1,B1 (one tile ahead).
// Wait chain: vmcnt(4) at P0/P1/P3 end, none at P2; epilogue tile 4->2->0.
// MODE 0: H = bf16(silu(xb[tok] @ W1T + b1));  MODE 1: y[tok] += wgt*(H @ W2T + b2)
template <int MODE>
__global__ __launch_bounds__(512) void k_gemm(const unsigned short* __restrict__ Abase,
                                              const unsigned short* __restrict__ WT,
                                              const float* __restrict__ bias,
                                              const int* __restrict__ counts,
                                              const int* __restrict__ tok,
                                              const float* __restrict__ wgt,
                                              unsigned short* __restrict__ Hout,
                                              float* __restrict__ y) {
    __shared__ __align__(16) char lds[131072];
    char* ldsp = (char*)lds;

    // bijective XCD swizzle: 2048 blocks, expert e pinned to one XCD
    int bid = blockIdx.x;
    int wg = (bid & 7) * 256 + (bid >> 3);
    int ct = wg & 3, rt = (wg >> 2) & 63, e = wg >> 8;

    int n_e = counts[e];
    int r0 = rt * 256;
    if (r0 >= n_e) return;
    int off_e = 0;
    #pragma unroll
    for (int j = 0; j < 8; ++j) off_e += (j < e) ? counts[j] : 0;
    int n0 = ct * 256;

    int t = threadIdx.x;
    int w = t >> 6, l = t & 63;
    int wqm = w >> 1, wqn = w & 1;        // within-quadrant: rows wqm*32, cols wqn*64

    // ---- staging sources (pre-swizzled global chunk: sc = c ^ (row&7)) ----
    int tr = t >> 3;                      // 0..63
    int sc = (t & 7) ^ (tr & 7);
    const char* srcA[4]; const char* srcB[4];
    #pragma unroll
    for (int ri = 0; ri < 4; ++ri) {      // ri -> half ri>>1, round ri&1 (rows ri*64+tr)
        int idx = r0 + ri * 64 + tr; if (idx > n_e - 1) idx = n_e - 1;
        long g = (MODE == 0) ? (long)tok[e * Btok + idx] : (long)(off_e + idx);
        srcA[ri] = (const char*)Abase + g * 2048 + sc * 16;
        srcB[ri] = (const char*)WT + ((long)e << 21) + (long)(n0 + ri * 64 + tr) * 2048 + sc * 16;
    }
    int dstoff = tr * 128 + (t & 7) * 16; // wave-uniform base + lane*16 (verified)

    // ---- fragment-read constants (same XOR on read) ----
    int rA = (wqm * 32 + (l & 15)) * 128;
    int rB = (wqn * 64 + (l & 15)) * 128;
    int x0 = ((l >> 4) ^ (l & 7)) << 4;
    int x1 = (((l >> 4) + 4) ^ (l & 7)) << 4;

    f32x4 acc[2][2][2][4];                // [qa][qb][mi][ni]
    #pragma unroll
    for (int qa = 0; qa < 2; ++qa)
        #pragma unroll
        for (int qb = 0; qb < 2; ++qb)
            #pragma unroll
            for (int mi = 0; mi < 2; ++mi)
                #pragma unroll
                for (int ni = 0; ni < 4; ++ni) acc[qa][qb][mi][ni] = {0.f, 0.f, 0.f, 0.f};

    short8 av[2][2], bv[4][2];            // [mi][ks], [ni][ks]

#define STAGE_A(h, nb) do { \
        char* d_ = ldsp + (nb) * 32768 + (h) * 16384 + dstoff; \
        gload16(srcA[2*(h)], d_); gload16(srcA[2*(h)+1], d_ + 8192); \
        srcA[2*(h)] += 128; srcA[2*(h)+1] += 128; } while (0)
#define STAGE_B(h, nb) do { \
        char* d_ = ldsp + 65536 + (nb) * 32768 + (h) * 16384 + dstoff; \
        gload16(srcB[2*(h)], d_); gload16(srcB[2*(h)+1], d_ + 8192); \
        srcB[2*(h)] += 128; srcB[2*(h)+1] += 128; } while (0)
#define READ_AV(qa, c) do { \
        const char* p_ = ldsp + (c) * 32768 + (qa) * 16384 + rA; \
        av[0][0] = *(const short8*)(p_ + x0);        av[0][1] = *(const short8*)(p_ + x1); \
        av[1][0] = *(const short8*)(p_ + 2048 + x0); av[1][1] = *(const short8*)(p_ + 2048 + x1); } while (0)
#define READ_BV(qb, c) do { \
        const char* p_ = ldsp + 65536 + (c) * 32768 + (qb) * 16384 + rB; \
        _Pragma("unroll") \
        for (int ni_ = 0; ni_ < 4; ++ni_) { \
            bv[ni_][0] = *(const short8*)(p_ + ni_ * 2048 + x0); \
            bv[ni_][1] = *(const short8*)(p_ + ni_ * 2048 + x1); } } while (0)
#define MFMA16(qa, qb) do { \
        __builtin_amdgcn_s_setprio(1); \
        _Pragma("unroll") \
        for (int mi_ = 0; mi_ < 2; ++mi_) \
            _Pragma("unroll") \
            for (int ni_ = 0; ni_ < 4; ++ni_) { \
                acc[qa][qb][mi_][ni_] = __builtin_amdgcn_mfma_f32_16x16x32_bf16(av[mi_][0], bv[ni_][0], acc[qa][qb][mi_][ni_], 0, 0, 0); \
                acc[qa][qb][mi_][ni_] = __builtin_amdgcn_mfma_f32_16x16x32_bf16(av[mi_][1], bv[ni_][1], acc[qa][qb][mi_][ni_], 0, 0, 0); } \
        __builtin_amdgcn_s_setprio(0); \
        __builtin_amdgcn_sched_barrier(0); } while (0)

    const int NT = Ddim / 64;             // 16 K-tiles
    // prologue: stage tile0 halves in need-order A0,B0,A1,B1 (8 loads)
    STAGE_A(0, 0); STAGE_B(0, 0); STAGE_A(1, 0); STAGE_B(1, 0);
    VMW(4); BARRIER();

    for (int kt = 0; kt < NT - 1; ++kt) {
        int c = kt & 1, nb = c ^ 1;
        // P0: quadrant (A0,B0)
        READ_AV(0, c); READ_BV(0, c);
        STAGE_A(0, nb);
        BARRIER();
        MFMA16(0, 0);
        VMW(4); BARRIER();
        // P1: quadrant (A1,B0)
        READ_AV(1, c);
        STAGE_B(0, nb);
        BARRIER();
        MFMA16(1, 0);
        VMW(4); BARRIER();
        // P2: quadrant (A1,B1)
        READ_BV(1, c);
        STAGE_A(1, nb);
        BARRIER();
        MFMA16(1, 1);
        BARRIER();
        // P3: quadrant (A0,B1)
        READ_AV(0, c);
        STAGE_B(1, nb);
        BARRIER();
        MFMA16(0, 1);
        VMW(4); BARRIER();
    }
    {   // epilogue tile (no staging): drain 4 -> 2 -> 0
        const int c = (NT - 1) & 1;
        READ_AV(0, c); READ_BV(0, c);
        BARRIER();
        MFMA16(0, 0);
        VMW(2); BARRIER();
        READ_AV(1, c);
        BARRIER();
        MFMA16(1, 0);
        VMW(0); BARRIER();
        READ_BV(1, c);
        BARRIER();
        MFMA16(1, 1);
        BARRIER();
        READ_AV(0, c);
        BARRIER();
        MFMA16(0, 1);
    }

    // ---- C-write epilogue ----
    float bias8[2][4];
    #pragma unroll
    for (int qb = 0; qb < 2; ++qb)
        #pragma unroll
        for (int ni = 0; ni < 4; ++ni)
            bias8[qb][ni] = bias[e * Ddim + n0 + qb * 128 + wqn * 64 + ni * 16 + (l & 15)];

    #pragma unroll
    for (int qa = 0; qa < 2; ++qa) {
        #pragma unroll
        for (int mi = 0; mi < 2; ++mi) {
            #pragma unroll
            for (int j = 0; j < 4; ++j) {
                int rl = qa * 128 + wqm * 32 + mi * 16 + (l >> 4) * 4 + j;
                int r = r0 + rl;
                bool ok = r < n_e;
                int trow = 0; float wr = 0.f;
                if (MODE == 1) {
                    int ri = ok ? r : 0;
                    trow = tok[e * Btok + ri];
                    wr = wgt[e * Btok + ri];
                }
                #pragma unroll
                for (int qb = 0; qb < 2; ++qb) {
                    #pragma unroll
                    for (int ni = 0; ni < 4; ++ni) {
                        int col = n0 + qb * 128 + wqn * 64 + ni * 16 + (l & 15);
                        float v = acc[qa][qb][mi][ni][j] + bias8[qb][ni];
                        if (MODE == 0) {
                            v = v / (1.f + __expf(-v));   // silu
                            if (ok) Hout[(long)(off_e + r) * Ddim + col] = f2bf(v);
                        } else {
                            if (ok) atomicAdd(&y[(long)trow * Ddim + col], wr * v);
                        }
                    }
                }
            }
        }
    }
#undef STAGE_A
#undef STAGE_B
#undef READ_AV
#undef READ_BV
#undef MFMA16
}

// ---------------- importance loss ----------------
__global__ __launch_bounds__(256) void k_loss(const float* __restrict__ impP,
                                              float* __restrict__ out) {
    __shared__ float red[256];
    __shared__ float impF[8];
    for (int e = 0; e < 8; ++e) {
        float s = 0.f;
        for (int i = threadIdx.x; i < 4096; i += 256) s += impP[i * 8 + e];
        red[threadIdx.x] = s;
        __syncthreads();
        for (int st = 128; st > 0; st >>= 1) {
            if ((int)threadIdx.x < st) red[threadIdx.x] += red[threadIdx.x + st];
            __syncthreads();
        }
        if (threadIdx.x == 0) impF[e] = red[0];
        __syncthreads();
    }
    if (threadIdx.x == 0) {
        double mean = 0.0;
        for (int e = 0; e < 8; ++e) mean += (double)impF[e];
        mean /= 8.0;
        double var = 0.0;
        for (int e = 0; e < 8; ++e) {
            double d = (double)impF[e] - mean;
            var += d * d;
        }
        var /= 7.0;   // ddof=1
        out[0] = (float)(0.01 * var / (mean * mean));
    }
}

// ---------------- launch ----------------
extern "C" void kernel_launch(void* const* d_in, const int* in_sizes, int n_in,
                              void* d_out, int out_size, void* d_ws, size_t ws_size,
                              hipStream_t stream) {
    const float* x  = (const float*)d_in[0];
    const float* q  = (const float*)d_in[1];
    const float* Wv = (const float*)d_in[2];
    const float* bv = (const float*)d_in[3];
    const float* Wo = (const float*)d_in[4];
    const float* bo = (const float*)d_in[5];
    const float* Wg = (const float*)d_in[6];
    const float* bg = (const float*)d_in[7];
    const float* W1 = (const float*)d_in[8];
    const float* b1 = (const float*)d_in[9];
    const float* W2 = (const float*)d_in[10];
    const float* b2 = (const float*)d_in[11];

    float* y = (float*)d_out;                       // [16384][1024]
    float* gate_prob = y + (long)Btok * Ddim;       // [16384][8]
    float* loss = gate_prob + (long)Btok * Eexp;    // [1]

    char* ws = (char*)d_ws;
    int*   counts = (int*)(ws + 0);                           // 32 B
    float* bcomb  = (float*)(ws + 256);                       // 32 B
    float* tmp    = (float*)(ws + 512);                       // 32 KB
    float* WcT    = (float*)(ws + 33280);                     // 32 KB
    float* impP   = (float*)(ws + 66048);                     // 128 KB
    int*   choice = (int*)(ws + 197120);                      // 64 KB
    float2* w12   = (float2*)(ws + 262656);                   // 128 KB
    int*   tok    = (int*)(ws + 393728);                      // 512 KB
    float* wgt    = (float*)(ws + 918016);                    // 512 KB
    unsigned short* xb   = (unsigned short*)(ws + 1442304);   // 32 MB
    unsigned short* w1bT = (unsigned short*)(ws + 34996736);  // 16 MB
    unsigned short* w2bT = (unsigned short*)(ws + 51773952);  // 16 MB
    unsigned short* H    = (unsigned short*)(ws + 68551168);  // 64 MB

    hipMemsetAsync(counts, 0, 32, stream);
    hipMemsetAsync(y, 0, (size_t)Btok * Ddim * sizeof(float), stream);

    k_tmp<<<32, 256, 0, stream>>>(Wo, Wg, tmp);
    k_wc <<<32, 256, 0, stream>>>(Wv, tmp, WcT);
    k_bc <<<1, 512, 0, stream>>>(bv, bo, bg, Wg, tmp, bcomb);
    k_convx<<<16384, 256, 0, stream>>>((const float4*)x, (ushort4*)xb);
    k_convw<<<16384, 256, 0, stream>>>(W1, W2, w1bT, w2bT);
    k_gate<<<4096, 256, 0, stream>>>(q, WcT, bcomb, gate_prob, choice, w12, impP);
    k_route<<<64, 256, 0, stream>>>(choice, w12, counts, tok, wgt);
    k_gemm<0><<<2048, 512, 0, stream>>>(xb, w1bT, b1, counts, tok, wgt, H, nullptr);
    k_gemm<1><<<2048, 512, 0, stream>>>(H, w2bT, b2, counts, tok, wgt, nullptr, y);
    k_loss<<<1, 256, 0, stream>>>(impP, loss);
}

// Round 5
// 454.417 us; speedup vs baseline: 1.1243x; 1.1243x over previous
//
#include <hip/hip_runtime.h>
#include <hip/hip_bf16.h>

// ---------------- constants ----------------
#define Btok 16384
#define Ddim 1024
#define Eexp 8

typedef __attribute__((ext_vector_type(8))) short short8;
typedef __attribute__((ext_vector_type(4))) float f32x4;

__device__ inline unsigned short f2bf(float f) {
    unsigned int u = __float_as_uint(f);
    unsigned int r = (u + 0x7fffu + ((u >> 16) & 1u)) >> 16;
    return (unsigned short)r;
}

__device__ inline void gload16(const void* g, void* l) {
    __builtin_amdgcn_global_load_lds(
        (const __attribute__((address_space(1))) void*)g,
        (__attribute__((address_space(3))) void*)l, 16, 0, 0);
}

// ---------------- tiny precompute kernels (f64 accum for gate accuracy) ----------------
// tmp[d][e] = sum_k Wo[d][k] * Wg[k][e]
__global__ __launch_bounds__(256) void k_tmp(const float* __restrict__ Wo,
                                             const float* __restrict__ Wg,
                                             float* __restrict__ tmp) {
    int id = blockIdx.x * 256 + threadIdx.x;   // 8192
    int d = id >> 3, e = id & 7;
    double s = 0.0;
    for (int k = 0; k < Ddim; ++k)
        s += (double)Wo[(long)d * Ddim + k] * (double)Wg[k * Eexp + e];
    tmp[id] = (float)s;
}

// WcT[e][d] = sum_k Wv[d][k] * tmp[k][e]
__global__ __launch_bounds__(256) void k_wc(const float* __restrict__ Wv,
                                            const float* __restrict__ tmp,
                                            float* __restrict__ WcT) {
    int id = blockIdx.x * 256 + threadIdx.x;   // 8192
    int d = id >> 3, e = id & 7;
    double s = 0.0;
    for (int k = 0; k < Ddim; ++k)
        s += (double)Wv[(long)d * Ddim + k] * (double)tmp[k * Eexp + e];
    WcT[e * Ddim + d] = (float)s;
}

// bcomb[e] = bv@tmp + bo@Wg + bg   (block of 512 = 8 waves, wave e)
__global__ __launch_bounds__(512) void k_bc(const float* __restrict__ bv,
                                            const float* __restrict__ bo,
                                            const float* __restrict__ bg,
                                            const float* __restrict__ Wg,
                                            const float* __restrict__ tmp,
                                            float* __restrict__ bcomb) {
    int w = threadIdx.x >> 6, l = threadIdx.x & 63;
    double s = 0.0;
    for (int k = l; k < Ddim; k += 64)
        s += (double)bv[k] * (double)tmp[k * Eexp + w] +
             (double)bo[k] * (double)Wg[k * Eexp + w];
    #pragma unroll
    for (int off = 32; off; off >>= 1) s += __shfl_xor(s, off);
    if (l == 0) bcomb[w] = (float)s + bg[w];
}

// ---------------- conversions ----------------
// x (f32) -> xb (bf16), 4 elems/thread
__global__ __launch_bounds__(256) void k_convx(const float4* __restrict__ x,
                                               ushort4* __restrict__ xb) {
    int i = blockIdx.x * 256 + threadIdx.x;
    float4 v = x[i];
    ushort4 o;
    o.x = f2bf(v.x); o.y = f2bf(v.y); o.z = f2bf(v.z); o.w = f2bf(v.w);
    xb[i] = o;
}

// W1,W2 (f32 [e][d][n]) -> transposed bf16 [e][n][d]
__global__ __launch_bounds__(256) void k_convw(const float* __restrict__ W1,
                                               const float* __restrict__ W2,
                                               unsigned short* __restrict__ w1bT,
                                               unsigned short* __restrict__ w2bT) {
    __shared__ float tile[32][33];
    int bid = blockIdx.x;             // 2*8*32*32 = 16384
    int arr = bid >> 13;
    int e = (bid >> 10) & 7, bi = (bid >> 5) & 31, bj = bid & 31;
    const float* src = (arr ? W2 : W1) + (long)e * Ddim * Ddim;
    unsigned short* dst = (arr ? w2bT : w1bT) + (long)e * Ddim * Ddim;
    int tr = threadIdx.x >> 5, tc = threadIdx.x & 31;
    #pragma unroll
    for (int i = 0; i < 4; ++i) {
        int dl = tr + i * 8;
        tile[dl][tc] = src[(long)(bi * 32 + dl) * Ddim + bj * 32 + tc];
    }
    __syncthreads();
    #pragma unroll
    for (int i = 0; i < 4; ++i) {
        int nl = tr + i * 8;
        dst[(long)(bj * 32 + nl) * Ddim + bi * 32 + tc] = f2bf(tile[tc][nl]);
    }
}

// ---------------- gate: logits -> softmax -> top2 (NO atomics) ----------------
__global__ __launch_bounds__(256) void k_gate(const float* __restrict__ q,
                                              const float* __restrict__ WcT,
                                              const float* __restrict__ bcomb,
                                              float* __restrict__ gate_prob,
                                              int* __restrict__ choice,
                                              float2* __restrict__ w12,
                                              float* __restrict__ impP) {
    __shared__ float impL[4][8];
    int w = threadIdx.x >> 6, l = threadIdx.x & 63;
    int t = blockIdx.x * 4 + w;
    const float* qr = q + (long)t * Ddim;
    float acc[8] = {0, 0, 0, 0, 0, 0, 0, 0};
    #pragma unroll
    for (int i = 0; i < 4; ++i) {
        float4 qv = *(const float4*)(qr + (i * 64 + l) * 4);
        #pragma unroll
        for (int e = 0; e < 8; ++e) {
            float4 wv = *(const float4*)(WcT + e * Ddim + (i * 64 + l) * 4);
            acc[e] += qv.x * wv.x + qv.y * wv.y + qv.z * wv.z + qv.w * wv.w;
        }
    }
    #pragma unroll
    for (int off = 32; off; off >>= 1)
        #pragma unroll
        for (int e = 0; e < 8; ++e) acc[e] += __shfl_xor(acc[e], off);
    // all lanes now hold full logits
    float lg[8], p[8];
    float m = -1e30f;
    #pragma unroll
    for (int e = 0; e < 8; ++e) { lg[e] = acc[e] + bcomb[e]; m = fmaxf(m, lg[e]); }
    float s = 0.f;
    #pragma unroll
    for (int e = 0; e < 8; ++e) { p[e] = expf(lg[e] - m); s += p[e]; }
    float inv = 1.f / s;
    #pragma unroll
    for (int e = 0; e < 8; ++e) p[e] *= inv;
    // top-2 (ties -> lower index, matching lax.top_k)
    float p1 = -1.f, p2 = -1.f; int i1 = 0, i2 = 0;
    #pragma unroll
    for (int e = 0; e < 8; ++e) {
        float pe = p[e];
        if (pe > p1) { p2 = p1; i2 = i1; p1 = pe; i1 = e; }
        else if (pe > p2) { p2 = pe; i2 = e; }
    }
    // softmax over the two PROBABILITY values (per reference)
    float ee = expf(p2 - p1);
    float wa = 1.f / (1.f + ee);
    float wb = ee / (1.f + ee);
    if (l == 0) {
        #pragma unroll
        for (int e = 0; e < 8; ++e) gate_prob[(long)t * 8 + e] = p[e];
        #pragma unroll
        for (int e = 0; e < 8; ++e) impL[w][e] = p[e];
        choice[t] = i1 | (i2 << 8);
        w12[t] = make_float2(wa, wb);
    }
    __syncthreads();
    if (threadIdx.x < 8)
        impP[blockIdx.x * 8 + threadIdx.x] =
            impL[0][threadIdx.x] + impL[1][threadIdx.x] +
            impL[2][threadIdx.x] + impL[3][threadIdx.x];
}

// ---------------- routing: hierarchical histogram + scatter ----------------
__global__ __launch_bounds__(256) void k_route(const int* __restrict__ choice,
                                               const float2* __restrict__ w12,
                                               int* __restrict__ counts,
                                               int* __restrict__ tok,
                                               float* __restrict__ wgt) {
    __shared__ int cnt[8];
    __shared__ int base[8];
    if (threadIdx.x < 8) cnt[threadIdx.x] = 0;
    __syncthreads();
    int t = blockIdx.x * 256 + threadIdx.x;
    int ch = choice[t];
    int i1 = ch & 255, i2 = ch >> 8;
    float2 ww = w12[t];
    int lp1 = atomicAdd(&cnt[i1], 1);
    int lp2 = atomicAdd(&cnt[i2], 1);
    __syncthreads();
    if (threadIdx.x < 8)
        base[threadIdx.x] = atomicAdd(&counts[threadIdx.x], cnt[threadIdx.x]);
    __syncthreads();
    int p1 = base[i1] + lp1;
    tok[i1 * Btok + p1] = t; wgt[i1 * Btok + p1] = ww.x;
    int p2 = base[i2] + lp2;
    tok[i2 * Btok + p2] = t; wgt[i2 * Btok + p2] = ww.y;
}

// ---------------- expert GEMMs: m97 structure ----------------
// 128x128 tile, BK=64, 4 waves, single-buffered 32KB LDS, 2-barrier K-loop,
// XOR-swizzled (conflict-free), 4 blocks/CU resident for inter-block overlap.
// MODE 0: H = bf16(silu(xb[tok] @ W1T + b1));  MODE 1: y[tok] += wgt*(H @ W2T + b2)
template <int MODE>
__global__ __launch_bounds__(256, 4) void k_gemm(const unsigned short* __restrict__ Abase,
                                                 const unsigned short* __restrict__ WT,
                                                 const float* __restrict__ bias,
                                                 const int* __restrict__ counts,
                                                 const int* __restrict__ tok,
                                                 const float* __restrict__ wgt,
                                                 unsigned short* __restrict__ Hout,
                                                 float* __restrict__ y) {
    __shared__ __align__(16) char lds[32768];   // A[128][128B] @0, B @16384
    char* ldsp = (char*)lds;

    // expert -> XCD pinning: e = bid&7 (HW round-robins bid%8 across XCDs)
    int bid = blockIdx.x;                 // 4096 = 8e * 64rt * 8ct
    int e = bid & 7;
    int k = bid >> 3;
    int rt = k >> 3, ct = k & 7;

    int n_e = counts[e];
    int r0 = rt * 128;
    if (r0 >= n_e) return;
    int off_e = 0;
    #pragma unroll
    for (int j = 0; j < 8; ++j) off_e += (j < e) ? counts[j] : 0;
    int n0 = ct * 128;

    int t = threadIdx.x;
    int w = t >> 6, l = t & 63;
    int wm = w >> 1, wn = w & 1;          // wave tile 64x64

    // ---- staging sources (pre-swizzled global chunk: sc = c ^ (row&7)) ----
    int tr = t >> 3;                      // 0..31 (row within a 32-row round)
    int sc = (t & 7) ^ (tr & 7);          // source 16B-chunk 0..7
    const char* srcA[4]; const char* srcB[4];
    #pragma unroll
    for (int ri = 0; ri < 4; ++ri) {      // rows ri*32 + tr
        int idx = r0 + ri * 32 + tr; if (idx > n_e - 1) idx = n_e - 1;
        long g = (MODE == 0) ? (long)tok[e * Btok + idx] : (long)(off_e + idx);
        srcA[ri] = (const char*)Abase + g * 2048 + sc * 16;
        srcB[ri] = (const char*)WT + ((long)e << 21) + (long)(n0 + ri * 32 + tr) * 2048 + sc * 16;
    }
    int dstoff = tr * 128 + (t & 7) * 16; // wave-uniform base + lane*16

    // ---- fragment-read constants (same XOR on read) ----
    int rA = (wm * 64 + (l & 15)) * 128;
    int rB = (wn * 64 + (l & 15)) * 128;
    int x0 = ((l >> 4) ^ (l & 7)) << 4;
    int x1 = (((l >> 4) + 4) ^ (l & 7)) << 4;

    f32x4 acc[4][4];
    #pragma unroll
    for (int mi = 0; mi < 4; ++mi)
        #pragma unroll
        for (int ni = 0; ni < 4; ++ni) acc[mi][ni] = {0.f, 0.f, 0.f, 0.f};

    const int NT = Ddim / 64;             // 16 K-steps
    for (int kk = 0; kk < NT; ++kk) {
        #pragma unroll
        for (int ri = 0; ri < 4; ++ri) {
            gload16(srcA[ri], ldsp + ri * 4096 + dstoff);
            gload16(srcB[ri], ldsp + 16384 + ri * 4096 + dstoff);
            srcA[ri] += 128; srcB[ri] += 128;
        }
        __syncthreads();                  // vmcnt(0) drain: tile in LDS
        #pragma unroll
        for (int ks = 0; ks < 2; ++ks) {
            int xo = ks ? x1 : x0;
            short8 av[4], bv[4];
            #pragma unroll
            for (int mi = 0; mi < 4; ++mi)
                av[mi] = *(const short8*)(ldsp + rA + mi * 2048 + xo);
            #pragma unroll
            for (int ni = 0; ni < 4; ++ni)
                bv[ni] = *(const short8*)(ldsp + 16384 + rB + ni * 2048 + xo);
            #pragma unroll
            for (int mi = 0; mi < 4; ++mi)
                #pragma unroll
                for (int ni = 0; ni < 4; ++ni)
                    acc[mi][ni] = __builtin_amdgcn_mfma_f32_16x16x32_bf16(av[mi], bv[ni], acc[mi][ni], 0, 0, 0);
        }
        __syncthreads();                  // all reads done before next stage
    }

    // ---- epilogue ----
    float bias4[4];
    #pragma unroll
    for (int ni = 0; ni < 4; ++ni)
        bias4[ni] = bias[e * Ddim + n0 + wn * 64 + ni * 16 + (l & 15)];

    #pragma unroll
    for (int mi = 0; mi < 4; ++mi) {
        #pragma unroll
        for (int j = 0; j < 4; ++j) {
            int rl = wm * 64 + mi * 16 + (l >> 4) * 4 + j;
            int r = r0 + rl;
            bool ok = r < n_e;
            int trow = 0; float wr = 0.f;
            if (MODE == 1) {
                int ri = ok ? r : 0;
                trow = tok[e * Btok + ri];
                wr = wgt[e * Btok + ri];
            }
            #pragma unroll
            for (int ni = 0; ni < 4; ++ni) {
                int col = n0 + wn * 64 + ni * 16 + (l & 15);
                float v = acc[mi][ni][j] + bias4[ni];
                if (MODE == 0) {
                    v = v / (1.f + __expf(-v));   // silu
                    if (ok) Hout[(long)(off_e + r) * Ddim + col] = f2bf(v);
                } else {
                    if (ok) atomicAdd(&y[(long)trow * Ddim + col], wr * v);
                }
            }
        }
    }
}

// ---------------- importance loss ----------------
__global__ __launch_bounds__(256) void k_loss(const float* __restrict__ impP,
                                              float* __restrict__ out) {
    __shared__ float red[256];
    __shared__ float impF[8];
    for (int e = 0; e < 8; ++e) {
        float s = 0.f;
        for (int i = threadIdx.x; i < 4096; i += 256) s += impP[i * 8 + e];
        red[threadIdx.x] = s;
        __syncthreads();
        for (int st = 128; st > 0; st >>= 1) {
            if ((int)threadIdx.x < st) red[threadIdx.x] += red[threadIdx.x + st];
            __syncthreads();
        }
        if (threadIdx.x == 0) impF[e] = red[0];
        __syncthreads();
    }
    if (threadIdx.x == 0) {
        double mean = 0.0;
        for (int e = 0; e < 8; ++e) mean += (double)impF[e];
        mean /= 8.0;
        double var = 0.0;
        for (int e = 0; e < 8; ++e) {
            double d = (double)impF[e] - mean;
            var += d * d;
        }
        var /= 7.0;   // ddof=1
        out[0] = (float)(0.01 * var / (mean * mean));
    }
}

// ---------------- launch ----------------
extern "C" void kernel_launch(void* const* d_in, const int* in_sizes, int n_in,
                              void* d_out, int out_size, void* d_ws, size_t ws_size,
                              hipStream_t stream) {
    const float* x  = (const float*)d_in[0];
    const float* q  = (const float*)d_in[1];
    const float* Wv = (const float*)d_in[2];
    const float* bv = (const float*)d_in[3];
    const float* Wo = (const float*)d_in[4];
    const float* bo = (const float*)d_in[5];
    const float* Wg = (const float*)d_in[6];
    const float* bg = (const float*)d_in[7];
    const float* W1 = (const float*)d_in[8];
    const float* b1 = (const float*)d_in[9];
    const float* W2 = (const float*)d_in[10];
    const float* b2 = (const float*)d_in[11];

    float* y = (float*)d_out;                       // [16384][1024]
    float* gate_prob = y + (long)Btok * Ddim;       // [16384][8]
    float* loss = gate_prob + (long)Btok * Eexp;    // [1]

    char* ws = (char*)d_ws;
    int*   counts = (int*)(ws + 0);                           // 32 B
    float* bcomb  = (float*)(ws + 256);                       // 32 B
    float* tmp    = (float*)(ws + 512);                       // 32 KB
    float* WcT    = (float*)(ws + 33280);                     // 32 KB
    float* impP   = (float*)(ws + 66048);                     // 128 KB
    int*   choice = (int*)(ws + 197120);                      // 64 KB
    float2* w12   = (float2*)(ws + 262656);                   // 128 KB
    int*   tok    = (int*)(ws + 393728);                      // 512 KB
    float* wgt    = (float*)(ws + 918016);                    // 512 KB
    unsigned short* xb   = (unsigned short*)(ws + 1442304);   // 32 MB
    unsigned short* w1bT = (unsigned short*)(ws + 34996736);  // 16 MB
    unsigned short* w2bT = (unsigned short*)(ws + 51773952);  // 16 MB
    unsigned short* H    = (unsigned short*)(ws + 68551168);  // 64 MB

    hipMemsetAsync(counts, 0, 32, stream);
    hipMemsetAsync(y, 0, (size_t)Btok * Ddim * sizeof(float), stream);

    k_tmp<<<32, 256, 0, stream>>>(Wo, Wg, tmp);
    k_wc <<<32, 256, 0, stream>>>(Wv, tmp, WcT);
    k_bc <<<1, 512, 0, stream>>>(bv, bo, bg, Wg, tmp, bcomb);
    k_convx<<<16384, 256, 0, stream>>>((const float4*)x, (ushort4*)xb);
    k_convw<<<16384, 256, 0, stream>>>(W1, W2, w1bT, w2bT);
    k_gate<<<4096, 256, 0, stream>>>(q, WcT, bcomb, gate_prob, choice, w12, impP);
    k_route<<<64, 256, 0, stream>>>(choice, w12, counts, tok, wgt);
    k_gemm<0><<<4096, 256, 0, stream>>>(xb, w1bT, b1, counts, tok, wgt, H, nullptr);
    k_gemm<1><<<4096, 256, 0, stream>>>(H, w2bT, b2, counts, tok, wgt, nullptr, y);
    k_loss<<<1, 256, 0, stream>>>(impP, loss);
}